// Round 1
// baseline (5809.665 us; speedup 1.0000x reference)
//
#include <hip/hip_runtime.h>
#include <math.h>

// Problem constants (B=2, T=2048, C=2048, H=16, HK=8, D=128, G=2)
constexpr int Bb = 2, Tt = 2048, Cc = 2048, Hh = 16, HKk = 8, Dd = 128, Gg = 2;

// ---------------------------------------------------------------------------
// Tiled fp32 GEMM: out = A[M,K] @ W[K,N]
// MODE 0: plain row-major out[M][N]
// MODE 1: QKV head layout: out[((b*Hx + h)*T + t)*D + d]  (h=n/D, d=n%D, b=m/T, t=m%T)
// Block: 256 threads, 64x64 tile, BK=16, 4x4 micro-tile per thread.
// ---------------------------------------------------------------------------
template<int MODE>
__global__ __launch_bounds__(256)
void gemm64(const float* __restrict__ A, const float* __restrict__ W,
            float* __restrict__ out, int K, int N, int Hx)
{
    __shared__ float As[16][68];   // [k][m], pad 68 -> 16B-aligned rows, 2-way max
    __shared__ float Bs[16][68];   // [k][n]

    const int tid = threadIdx.x;
    const int tx = tid & 15, ty = tid >> 4;
    const int bn = blockIdx.x * 64, bm = blockIdx.y * 64;

    const int am = tid >> 4;   // row group for A loads
    const int ak = tid & 15;   // k for A loads
    const int bk = tid >> 6;   // k group for B loads
    const int bc = tid & 63;   // n for B loads

    float c[4][4] = {};

    for (int kt = 0; kt < K; kt += 16) {
        #pragma unroll
        for (int i = 0; i < 4; i++) {
            int m = am + i * 16;
            As[ak][m] = A[(size_t)(bm + m) * K + kt + ak];
        }
        #pragma unroll
        for (int i = 0; i < 4; i++) {
            int k = bk + i * 4;
            Bs[k][bc] = W[(size_t)(kt + k) * N + bn + bc];
        }
        __syncthreads();
        #pragma unroll
        for (int k = 0; k < 16; k++) {
            float4 av = *(const float4*)&As[k][ty * 4];
            float4 bv = *(const float4*)&Bs[k][tx * 4];
            float a[4] = {av.x, av.y, av.z, av.w};
            float b[4] = {bv.x, bv.y, bv.z, bv.w};
            #pragma unroll
            for (int i = 0; i < 4; i++)
                #pragma unroll
                for (int j = 0; j < 4; j++)
                    c[i][j] = fmaf(a[i], b[j], c[i][j]);
        }
        __syncthreads();
    }

    #pragma unroll
    for (int i = 0; i < 4; i++) {
        int m = bm + ty * 4 + i;
        int b = m / Tt, t = m % Tt;
        int n = bn + tx * 4;
        float4 v = make_float4(c[i][0], c[i][1], c[i][2], c[i][3]);
        if (MODE == 0) {
            *(float4*)&out[(size_t)m * N + n] = v;
        } else {
            int h = n / Dd, d = n % Dd;
            *(float4*)&out[(((size_t)b * Hx + h) * Tt + t) * Dd + d] = v;
        }
    }
}

// ---------------------------------------------------------------------------
// RoPE applied in place to Q [B,H,T,D] and K [B,HK,T,D].
// One thread per (b, head-union, t, i) with i in [0,64): handles pair (i, i+64).
// ---------------------------------------------------------------------------
__global__ __launch_bounds__(256)
void rope_kernel(float* __restrict__ Q, float* __restrict__ Kv,
                 const int* __restrict__ positions)
{
    int idx = blockIdx.x * 256 + threadIdx.x;
    int i = idx & 63;
    int rest = idx >> 6;
    int t = rest % Tt;
    int bh = rest / Tt;                 // 0 .. B*(H+HK)-1
    int b = bh / (Hh + HKk);
    int h = bh % (Hh + HKk);

    float* base = (h < Hh)
        ? Q  + (((size_t)b * Hh  + h)        * Tt + t) * Dd
        : Kv + (((size_t)b * HKk + (h - Hh)) * Tt + t) * Dd;

    float pos = (float)positions[t];
    // theta_i = 10000^(2i/128);  inv_theta = exp(-(2i/128)*ln(10000))
    float inv_theta = expf(-(2.0f * (float)i / 128.0f) * 9.210340371976184f);
    float f = pos * inv_theta;
    float s = sinf(f), co = cosf(f);    // accurate range reduction (f up to ~2047)

    float x1 = base[i], x2 = base[i + 64];
    base[i]      = fmaf(x1, co, -x2 * s);
    base[i + 64] = fmaf(x2, co,  x1 * s);
}

// ---------------------------------------------------------------------------
// Flash attention, fp32. Grid: (T/32, H, B). Block: 256 threads (4 waves).
// Q tile 32x128 (pre-scaled), K/V tiles 32x128, online softmax.
// Score phase: thread -> (key s = tid&31, rows tid>>5 + 8p).
// Softmax/PV phase: thread -> (row r = tid>>3, 16 d-cols at (tid&7)*16).
// Causal masking at element level inside the diagonal tile; tiles > qtile skipped.
// Output written as attn buffer [B, T, H, D] (ready for the Wo GEMM).
// ---------------------------------------------------------------------------
__global__ __launch_bounds__(256)
void attn_kernel(const float* __restrict__ Q, const float* __restrict__ K,
                 const float* __restrict__ V, float* __restrict__ O)
{
    __shared__ float Qs[32][132];
    __shared__ float Ks[32][132];
    __shared__ float Vs[32][132];
    __shared__ float Ps[32][36];

    const int tid = threadIdx.x;
    const int qtile = blockIdx.x;
    const int h = blockIdx.y;
    const int b = blockIdx.z;
    const int hk = h / Gg;
    const float scale = 0.08838834764831845f;  // 1/sqrt(128)

    const float* Qbase = Q + (((size_t)b * Hh  + h ) * Tt) * Dd;
    const float* Kbase = K + (((size_t)b * HKk + hk) * Tt) * Dd;
    const float* Vbase = V + (((size_t)b * HKk + hk) * Tt) * Dd;

    // Load + scale Q tile
    {
        int flat = tid * 4;
        #pragma unroll
        for (int p = 0; p < 4; p++) {
            int f = flat + p * 1024;
            int r = f >> 7, cc = f & 127;
            float4 v = *(const float4*)&Qbase[(size_t)(qtile * 32 + r) * Dd + cc];
            Qs[r][cc + 0] = v.x * scale;
            Qs[r][cc + 1] = v.y * scale;
            Qs[r][cc + 2] = v.z * scale;
            Qs[r][cc + 3] = v.w * scale;
        }
    }

    const int r_own = tid >> 3;           // row owned in softmax/PV
    const int dgrp  = (tid & 7) * 16;     // 16 d-columns owned
    const int s_sc  = tid & 31;           // score-phase key
    const int r0_sc = tid >> 5;           // score-phase base row

    float acc[16] = {};
    float mrow = -INFINITY, lrow = 0.0f;

    for (int kt = 0; kt <= qtile; kt++) {
        __syncthreads();   // protect Ks/Vs/Ps reuse from previous iteration
        // Load K, V tiles
        {
            int flat = tid * 4;
            #pragma unroll
            for (int p = 0; p < 4; p++) {
                int f = flat + p * 1024;
                int r = f >> 7, cc = f & 127;
                *(float4*)&Ks[r][cc] = *(const float4*)&Kbase[(size_t)(kt * 32 + r) * Dd + cc];
                *(float4*)&Vs[r][cc] = *(const float4*)&Vbase[(size_t)(kt * 32 + r) * Dd + cc];
            }
        }
        __syncthreads();

        // Scores: 4 rows per thread, one key column
        #pragma unroll
        for (int p = 0; p < 4; p++) {
            int r = r0_sc + p * 8;
            float dot = 0.f;
            #pragma unroll
            for (int d4 = 0; d4 < 128; d4 += 4) {
                float4 qv = *(const float4*)&Qs[r][d4];
                float4 kv = *(const float4*)&Ks[s_sc][d4];
                dot = fmaf(qv.x, kv.x, dot);
                dot = fmaf(qv.y, kv.y, dot);
                dot = fmaf(qv.z, kv.z, dot);
                dot = fmaf(qv.w, kv.w, dot);
            }
            int qg = qtile * 32 + r, sg = kt * 32 + s_sc;
            Ps[r][s_sc] = (sg <= qg) ? dot : -1e30f;
        }
        __syncthreads();

        // Online softmax: 8 threads per row (same wave), width-8 shuffles
        {
            float sc[4];
            float lmax = -INFINITY;
            #pragma unroll
            for (int q = 0; q < 4; q++) {
                sc[q] = Ps[r_own][(tid & 7) * 4 + q];
                lmax = fmaxf(lmax, sc[q]);
            }
            #pragma unroll
            for (int o = 4; o >= 1; o >>= 1)
                lmax = fmaxf(lmax, __shfl_xor(lmax, o, 8));
            float mnew = fmaxf(mrow, lmax);
            float fac = __expf(mrow - mnew);  // exp(-inf)=0 on first tile
            float lsum = 0.f;
            #pragma unroll
            for (int q = 0; q < 4; q++) {
                sc[q] = __expf(sc[q] - mnew);
                lsum += sc[q];
            }
            #pragma unroll
            for (int q = 0; q < 4; q++)
                Ps[r_own][(tid & 7) * 4 + q] = sc[q];
            #pragma unroll
            for (int o = 4; o >= 1; o >>= 1)
                lsum += __shfl_xor(lsum, o, 8);
            lrow = lrow * fac + lsum;
            mrow = mnew;
            #pragma unroll
            for (int j = 0; j < 16; j++) acc[j] *= fac;
        }
        __syncthreads();   // safety: make P writes visible before PV reads

        // PV: acc[r_own][dgrp..dgrp+15] += sum_s P[r_own][s] * V[s][:]
        #pragma unroll 4
        for (int s = 0; s < 32; s++) {
            float p = Ps[r_own][s];
            #pragma unroll
            for (int j4 = 0; j4 < 16; j4 += 4) {
                float4 vv = *(const float4*)&Vs[s][dgrp + j4];
                acc[j4 + 0] = fmaf(p, vv.x, acc[j4 + 0]);
                acc[j4 + 1] = fmaf(p, vv.y, acc[j4 + 1]);
                acc[j4 + 2] = fmaf(p, vv.z, acc[j4 + 2]);
                acc[j4 + 3] = fmaf(p, vv.w, acc[j4 + 3]);
            }
        }
    }

    // Write normalized output into attn buffer [B, T, H, D]
    {
        int t = qtile * 32 + r_own;
        float inv = 1.0f / lrow;
        float* op = O + (((size_t)b * Tt + t) * Hh + h) * Dd + dgrp;
        #pragma unroll
        for (int j4 = 0; j4 < 16; j4 += 4) {
            float4 v = make_float4(acc[j4] * inv, acc[j4 + 1] * inv,
                                   acc[j4 + 2] * inv, acc[j4 + 3] * inv);
            *(float4*)&op[j4] = v;
        }
    }
}

// ---------------------------------------------------------------------------
// Launch
// ---------------------------------------------------------------------------
extern "C" void kernel_launch(void* const* d_in, const int* in_sizes, int n_in,
                              void* d_out, int out_size, void* d_ws, size_t ws_size,
                              hipStream_t stream)
{
    const float* x  = (const float*)d_in[0];
    // d_in[1] = attn_mask (all-true, ignored)
    const int*   pos = (const int*)d_in[2];
    const float* Wq = (const float*)d_in[3];
    const float* Wk = (const float*)d_in[4];
    const float* Wv = (const float*)d_in[5];
    const float* Wo = (const float*)d_in[6];
    float* out = (float*)d_out;

    // Workspace layout (floats):
    //   Q    [B,H,T,D]   = 8,388,608
    //   K    [B,HK,T,D]  = 4,194,304
    //   V    [B,HK,T,D]  = 4,194,304
    //   attn [B,T,H,D]   = 8,388,608
    float* Qw = (float*)d_ws;
    float* Kw = Qw + (size_t)Bb * Hh  * Tt * Dd;
    float* Vw = Kw + (size_t)Bb * HKk * Tt * Dd;
    float* Aw = Vw + (size_t)Bb * HKk * Tt * Dd;

    dim3 blk(256);

    // QKV projections (write head-major layouts directly)
    gemm64<1><<<dim3(32, 64), blk, 0, stream>>>(x, Wq, Qw, Cc, Hh  * Dd, Hh);
    gemm64<1><<<dim3(16, 64), blk, 0, stream>>>(x, Wk, Kw, Cc, HKk * Dd, HKk);
    gemm64<1><<<dim3(16, 64), blk, 0, stream>>>(x, Wv, Vw, Cc, HKk * Dd, HKk);

    // RoPE on Q and K
    {
        int total = Bb * (Hh + HKk) * Tt * 64;
        rope_kernel<<<total / 256, blk, 0, stream>>>(Qw, Kw, pos);
    }

    // Causal GQA flash attention -> attn buffer [B,T,H,D]
    attn_kernel<<<dim3(Tt / 32, Hh, Bb), blk, 0, stream>>>(Qw, Kw, Vw, Aw);

    // Output projection
    gemm64<0><<<dim3(32, 64), blk, 0, stream>>>(Aw, Wo, out, Hh * Dd, Cc, 0);
}

// Round 4
// 1851.592 us; speedup vs baseline: 3.1377x; 3.1377x over previous
//
#include <hip/hip_runtime.h>
#include <math.h>

constexpr int Bb = 2, Tt = 2048, Cc = 2048, Hh = 16, HKk = 8, Dd = 128, Gg = 2;

typedef short  bf16x8 __attribute__((ext_vector_type(8)));   // 8 bf16 = 4 VGPR
typedef ushort u16x8  __attribute__((ext_vector_type(8)));
typedef float  f32x4  __attribute__((ext_vector_type(4)));

#define MFMA_16x16x32 __builtin_amdgcn_mfma_f32_16x16x32_bf16

__device__ __forceinline__ ushort f2bf(float f) {            // RNE, finite inputs
    uint u = __float_as_uint(f);
    u += 0x7fffu + ((u >> 16) & 1u);
    return (ushort)(u >> 16);
}
__device__ __forceinline__ float bf2f(ushort h) {
    return __uint_as_float(((uint)h) << 16);
}

// ---------------------------------------------------------------------------
// Tiled fp32 GEMM: out = A[M,K] @ W[K,N].  64x64 tile, BK=16, 4x4 micro-tile.
// MODE 0: fp32 row-major out
// MODE 1: bf16 hi/lo pair, head layout [B,Hx,T,D]
// MODE 3: bf16 HI ONLY, V transposed [B,HK,D,T]
// ---------------------------------------------------------------------------
template<int MODE>
__global__ __launch_bounds__(256)
void gemm64(const float* __restrict__ A, const float* __restrict__ W,
            float* __restrict__ outf, ushort* __restrict__ o_hi,
            ushort* __restrict__ o_lo, int K, int N, int Hx)
{
    __shared__ float As[16][68];
    __shared__ float Bs[16][68];

    const int tid = threadIdx.x;
    const int tx = tid & 15, ty = tid >> 4;
    const int bn = blockIdx.x * 64, bm = blockIdx.y * 64;

    const int am = tid >> 4, ak = tid & 15;
    const int bk = tid >> 6, bc = tid & 63;

    float c[4][4] = {};

    for (int kt = 0; kt < K; kt += 16) {
        #pragma unroll
        for (int i = 0; i < 4; i++) {
            int m = am + i * 16;
            As[ak][m] = A[(size_t)(bm + m) * K + kt + ak];
        }
        #pragma unroll
        for (int i = 0; i < 4; i++) {
            int k = bk + i * 4;
            Bs[k][bc] = W[(size_t)(kt + k) * N + bn + bc];
        }
        __syncthreads();
        #pragma unroll
        for (int k = 0; k < 16; k++) {
            float4 av = *(const float4*)&As[k][ty * 4];
            float4 bv = *(const float4*)&Bs[k][tx * 4];
            float a[4] = {av.x, av.y, av.z, av.w};
            float b[4] = {bv.x, bv.y, bv.z, bv.w};
            #pragma unroll
            for (int i = 0; i < 4; i++)
                #pragma unroll
                for (int j = 0; j < 4; j++)
                    c[i][j] = fmaf(a[i], b[j], c[i][j]);
        }
        __syncthreads();
    }

    if (MODE == 0) {
        #pragma unroll
        for (int i = 0; i < 4; i++) {
            int m = bm + ty * 4 + i;
            int n = bn + tx * 4;
            *(float4*)&outf[(size_t)m * N + n] =
                make_float4(c[i][0], c[i][1], c[i][2], c[i][3]);
        }
    } else if (MODE == 1) {
        #pragma unroll
        for (int i = 0; i < 4; i++) {
            int m = bm + ty * 4 + i;
            int b = m / Tt, t = m % Tt;
            int n = bn + tx * 4;
            int h = n >> 7, d = n & 127;
            size_t off = (((size_t)b * Hx + h) * Tt + t) * Dd + d;
            ushort4 hv, lv;
            float v0;
            v0 = c[i][0]; hv.x = f2bf(v0); lv.x = f2bf(v0 - bf2f(hv.x));
            v0 = c[i][1]; hv.y = f2bf(v0); lv.y = f2bf(v0 - bf2f(hv.y));
            v0 = c[i][2]; hv.z = f2bf(v0); lv.z = f2bf(v0 - bf2f(hv.z));
            v0 = c[i][3]; hv.w = f2bf(v0); lv.w = f2bf(v0 - bf2f(hv.w));
            *(ushort4*)&o_hi[off] = hv;
            *(ushort4*)&o_lo[off] = lv;
        }
    } else { // MODE 3: V transposed [B,HK,D,T], hi only
        int m0 = bm + ty * 4;
        int b = m0 / Tt, t0 = m0 % Tt;
        #pragma unroll
        for (int j = 0; j < 4; j++) {
            int n = bn + tx * 4 + j;
            int hk = n >> 7, d = n & 127;
            size_t off = (((size_t)b * HKk + hk) * Dd + d) * Tt + t0;
            ushort4 hv;
            hv.x = f2bf(c[0][j]);
            hv.y = f2bf(c[1][j]);
            hv.z = f2bf(c[2][j]);
            hv.w = f2bf(c[3][j]);
            *(ushort4*)&o_hi[off] = hv;
        }
    }
}

// ---------------------------------------------------------------------------
// RoPE in place on bf16 hi/lo Q [B,H,T,D] and K [B,HK,T,D].
// ---------------------------------------------------------------------------
__global__ __launch_bounds__(256)
void rope_kernel(ushort* __restrict__ Qhi, ushort* __restrict__ Qlo,
                 ushort* __restrict__ Khi, ushort* __restrict__ Klo,
                 const int* __restrict__ positions)
{
    int idx = blockIdx.x * 256 + threadIdx.x;
    int i = idx & 63;
    int rest = idx >> 6;
    int t = rest % Tt;
    int bh = rest / Tt;
    int b = bh / (Hh + HKk);
    int h = bh % (Hh + HKk);

    ushort *hi, *lo;
    if (h < Hh) {
        size_t off = (((size_t)b * Hh + h) * Tt + t) * Dd;
        hi = Qhi + off; lo = Qlo + off;
    } else {
        size_t off = (((size_t)b * HKk + (h - Hh)) * Tt + t) * Dd;
        hi = Khi + off; lo = Klo + off;
    }

    float pos = (float)positions[t];
    float inv_theta = expf(-(2.0f * (float)i / 128.0f) * 9.210340371976184f);
    float f = pos * inv_theta;
    float s = sinf(f), co = cosf(f);

    float x1 = bf2f(hi[i])      + bf2f(lo[i]);
    float x2 = bf2f(hi[i + 64]) + bf2f(lo[i + 64]);
    float y1 = fmaf(x1, co, -x2 * s);
    float y2 = fmaf(x2, co,  x1 * s);

    ushort h1 = f2bf(y1); hi[i]      = h1; lo[i]      = f2bf(y1 - bf2f(h1));
    ushort h2 = f2bf(y2); hi[i + 64] = h2; lo[i + 64] = f2bf(y2 - bf2f(h2));
}

// ---------------------------------------------------------------------------
// Split-bf16 MFMA flash attention.
// Grid (16, H, B), block 256 = 4 waves. Q-tile 128 rows (32/wave), KV tile 64.
// S  = (Qhi+Qlo)(Khi+Klo)^T via 3 MFMAs (score accuracy matters: feeds exp).
// PV = P_bf16 * V_bf16 via 1 MFMA (convex combo: bf16 error ~2^-9, harmless).
// LDS 64 KB: Khi 16K | Klo 16K | Vthi 16K | P 4 waves x 4K (32x64 bf16).
// FIX vs round 3: P scratch properly sized (4 KB/wave, was 2 KB -> overlap
// corruption + out-of-bounds LDS, the actual source of the 5.95 absmax).
// ---------------------------------------------------------------------------
__global__ __launch_bounds__(256, 2)
void attn_mfma(const ushort* __restrict__ Qhi, const ushort* __restrict__ Qlo,
               const ushort* __restrict__ Khi, const ushort* __restrict__ Klo,
               const ushort* __restrict__ Vthi,
               float* __restrict__ O)
{
    __shared__ __align__(16) char smem[65536];

    const int tid  = threadIdx.x;
    const int w    = tid >> 6, lane = tid & 63;
    const int g16  = lane >> 4, l16 = lane & 15;

    // qt remap: co-resident blocks get complementary causal lengths
    int xb = blockIdx.x;
    int base = (xb & 1) ? 15 - (xb >> 1) : (xb >> 1);
    const int qt = blockIdx.z ? 15 - base : base;
    const int h = blockIdx.y, b = blockIdx.z, hk = h >> 1;

    // Q fragments (A-layout: row = l16, k = 8*g16 + i + 32*kf)
    bf16x8 qh[2][4], ql[2][4];
    {
        size_t qoff = (((size_t)b * Hh + h) * Tt + (size_t)qt * 128 + w * 32) * Dd;
        #pragma unroll
        for (int m = 0; m < 2; m++)
            #pragma unroll
            for (int kf = 0; kf < 4; kf++) {
                size_t o = qoff + (size_t)(m * 16 + l16) * Dd + g16 * 8 + kf * 32;
                qh[m][kf] = *(const bf16x8*)(Qhi + o);
                ql[m][kf] = *(const bf16x8*)(Qlo + o);
            }
    }

    const ushort* ksrc = (w == 0 ? Khi : Klo) + ((size_t)b * HKk + hk) * Tt * Dd;
    const ushort* vsrc = Vthi + ((size_t)b * HKk + hk) * Dd * Tt;
    char* Pbase = &smem[49152 + w * 4096];   // 32 rows x 128 B, hi only

    f32x4 acc[2][8];
    #pragma unroll
    for (int m = 0; m < 2; m++)
        #pragma unroll
        for (int nt = 0; nt < 8; nt++) acc[m][nt] = (f32x4)0.f;

    float mrun[8], lrun[8];
    #pragma unroll
    for (int i = 0; i < 8; i++) { mrun[i] = -INFINITY; lrun[i] = 0.f; }

    const int nkt    = 2 * qt + 2;
    const int qfirst = qt * 128 + w * 32;
    const int qlast  = qfirst + 31;
    const int prow0  = qfirst + 4 * g16;
    const float scl = 0.08838834764831845f;   // 1/sqrt(128)

    for (int kt = 0; kt < nkt; kt++) {
        __syncthreads();
        // ---- stage KV tile: w0->Khi, w1->Klo, w2/w3 -> Vthi halves ----
        if (w < 2) {
            int r0 = lane >> 4, g = lane & 15;
            #pragma unroll
            for (int i = 0; i < 16; i++) {
                int row = 4 * i + r0;
                const ushort* s = ksrc + (size_t)(kt * 64 + row) * Dd
                                       + ((g ^ (row & 7)) * 8);
                u16x8 v = *(const u16x8*)s;
                *(u16x8*)&smem[w * 16384 + i * 1024 + lane * 16] = v;
            }
        } else {
            int r0 = lane >> 3, g = lane & 7;
            #pragma unroll
            for (int ii = 0; ii < 8; ii++) {
                int i = ii + (w - 2) * 8;
                int row = 8 * i + r0;                       // d
                const ushort* s = vsrc + (size_t)row * Tt + kt * 64
                                       + ((g ^ (row & 7)) * 8);
                u16x8 v = *(const u16x8*)s;
                *(u16x8*)&smem[32768 + i * 1024 + lane * 16] = v;
            }
        }
        __syncthreads();

        if (kt * 64 > qlast) continue;    // wave-uniform skip (barriers balanced)

        // ---- S = Q K^T (split: hi*hi + hi*lo + lo*hi) ----
        f32x4 s[2][4];
        #pragma unroll
        for (int m = 0; m < 2; m++)
            #pragma unroll
            for (int nt = 0; nt < 4; nt++) s[m][nt] = (f32x4)0.f;

        #pragma unroll
        for (int kf = 0; kf < 4; kf++) {
            #pragma unroll
            for (int nt = 0; nt < 4; nt++) {
                int row = l16 + nt * 16;                    // key
                int byte = row * 256 + (((g16 + 4 * kf) ^ (row & 7)) * 16);
                bf16x8 kh = *(const bf16x8*)&smem[byte];
                bf16x8 kl = *(const bf16x8*)&smem[16384 + byte];
                #pragma unroll
                for (int m = 0; m < 2; m++) {
                    s[m][nt] = MFMA_16x16x32(qh[m][kf], kh, s[m][nt], 0, 0, 0);
                    s[m][nt] = MFMA_16x16x32(qh[m][kf], kl, s[m][nt], 0, 0, 0);
                    s[m][nt] = MFMA_16x16x32(ql[m][kf], kh, s[m][nt], 0, 0, 0);
                }
            }
        }

        // scale + causal mask: gate on the wave's FIRST row
        bool partial = (kt * 64 + 63 > qfirst);
        #pragma unroll
        for (int m = 0; m < 2; m++)
            #pragma unroll
            for (int nt = 0; nt < 4; nt++) {
                s[m][nt] *= scl;
                if (partial) {
                    int col = kt * 64 + nt * 16 + l16;
                    #pragma unroll
                    for (int r = 0; r < 4; r++) {
                        int row = prow0 + m * 16 + r;
                        if (col > row) s[m][nt][r] = -INFINITY;
                    }
                }
            }

        // ---- online softmax (rows live in 16-lane groups) ----
        #pragma unroll
        for (int m = 0; m < 2; m++)
            #pragma unroll
            for (int r = 0; r < 4; r++) {
                float mx = fmaxf(fmaxf(s[m][0][r], s[m][1][r]),
                                 fmaxf(s[m][2][r], s[m][3][r]));
                #pragma unroll
                for (int o = 1; o < 16; o <<= 1)
                    mx = fmaxf(mx, __shfl_xor(mx, o, 16));
                int ri = m * 4 + r;
                float mn  = fmaxf(mrun[ri], mx);
                float fac = __expf(mrun[ri] - mn);  // exp(-inf)=0 on first tile
                float sum = 0.f;
                #pragma unroll
                for (int nt = 0; nt < 4; nt++) {
                    float pv = __expf(s[m][nt][r] - mn);
                    s[m][nt][r] = pv;
                    sum += pv;
                }
                #pragma unroll
                for (int o = 1; o < 16; o <<= 1)
                    sum += __shfl_xor(sum, o, 16);
                lrun[ri] = lrun[ri] * fac + sum;
                mrun[ri] = mn;
                #pragma unroll
                for (int nt = 0; nt < 8; nt++) acc[m][nt][r] *= fac;
            }

        // ---- P -> bf16 -> wave-private swizzled LDS (32 rows x 128 B) ----
        #pragma unroll
        for (int m = 0; m < 2; m++)
            #pragma unroll
            for (int nt = 0; nt < 4; nt++)
                #pragma unroll
                for (int r = 0; r < 4; r++) {
                    int row = m * 16 + 4 * g16 + r;         // 0..31
                    int byte = (row * 128 + (nt * 16 + l16) * 2) ^ ((row & 7) << 4);
                    *(ushort*)(Pbase + byte) = f2bf(s[m][nt][r]);
                }

        // ---- PV (single bf16) ----
        #pragma unroll
        for (int kf = 0; kf < 2; kf++) {
            bf16x8 pa[2];
            #pragma unroll
            for (int m = 0; m < 2; m++) {
                int row = m * 16 + l16;
                int byte = (row * 128 + (g16 + 4 * kf) * 16) ^ ((row & 7) << 4);
                pa[m] = *(const bf16x8*)(Pbase + byte);
            }
            #pragma unroll
            for (int nt = 0; nt < 8; nt++) {
                int row = l16 + nt * 16;                    // d
                int byte = 32768 + row * 128 + (((g16 + 4 * kf) ^ (row & 7)) * 16);
                bf16x8 vh = *(const bf16x8*)&smem[byte];
                #pragma unroll
                for (int m = 0; m < 2; m++)
                    acc[m][nt] = MFMA_16x16x32(pa[m], vh, acc[m][nt], 0, 0, 0);
            }
        }
    }

    // ---- epilogue: normalize, write fp32 attn buffer [B,T,H,D] ----
    #pragma unroll
    for (int m = 0; m < 2; m++)
        #pragma unroll
        for (int r = 0; r < 4; r++) {
            float inv = 1.0f / lrun[m * 4 + r];
            int t = qt * 128 + w * 32 + m * 16 + 4 * g16 + r;
            float* op = O + (((size_t)b * Tt + t) * Hh + h) * Dd + l16;
            #pragma unroll
            for (int nt = 0; nt < 8; nt++)
                op[nt * 16] = acc[m][nt][r] * inv;
        }
}

// ---------------------------------------------------------------------------
// Launch
// ---------------------------------------------------------------------------
extern "C" void kernel_launch(void* const* d_in, const int* in_sizes, int n_in,
                              void* d_out, int out_size, void* d_ws, size_t ws_size,
                              hipStream_t stream)
{
    const float* x  = (const float*)d_in[0];
    const int*   pos = (const int*)d_in[2];
    const float* Wq = (const float*)d_in[3];
    const float* Wk = (const float*)d_in[4];
    const float* Wv = (const float*)d_in[5];
    const float* Wo = (const float*)d_in[6];
    float* out = (float*)d_out;

    // ws layout (bytes):
    //   Qhi 16.78M | Qlo 16.78M | Khi 8.39M | Klo 8.39M | Vthi 8.39M | (gap 8.39M)
    //   Aw fp32 33.55M
    char* p = (char*)d_ws;
    ushort* Qhi  = (ushort*)(p);
    ushort* Qlo  = (ushort*)(p + 16777216);
    ushort* Khi  = (ushort*)(p + 33554432);
    ushort* Klo  = (ushort*)(p + 41943040);
    ushort* Vthi = (ushort*)(p + 50331648);
    float*  Aw   = (float* )(p + 67108864);

    dim3 blk(256);

    gemm64<1><<<dim3(32, 64), blk, 0, stream>>>(x, Wq, nullptr, Qhi, Qlo, Cc, Hh * Dd, Hh);
    gemm64<1><<<dim3(16, 64), blk, 0, stream>>>(x, Wk, nullptr, Khi, Klo, Cc, HKk * Dd, HKk);
    gemm64<3><<<dim3(16, 64), blk, 0, stream>>>(x, Wv, nullptr, Vthi, nullptr, Cc, HKk * Dd, HKk);

    {
        int total = Bb * (Hh + HKk) * Tt * 64;
        rope_kernel<<<total / 256, blk, 0, stream>>>(Qhi, Qlo, Khi, Klo, pos);
    }

    attn_mfma<<<dim3(16, Hh, Bb), blk, 0, stream>>>(Qhi, Qlo, Khi, Klo, Vthi, Aw);

    gemm64<0><<<dim3(32, 64), blk, 0, stream>>>(Aw, Wo, out, nullptr, nullptr, Hh * Dd, Cc, 0);
}

// Round 8
// 732.121 us; speedup vs baseline: 7.9354x; 2.5291x over previous
//
#include <hip/hip_runtime.h>
#include <math.h>

constexpr int Bb = 2, Tt = 2048, Cc = 2048, Hh = 16, HKk = 8, Dd = 128, Gg = 2;

typedef short  bf16x8 __attribute__((ext_vector_type(8)));   // 8 bf16 = 4 VGPR
typedef ushort u16x8  __attribute__((ext_vector_type(8)));
typedef float  f32x4  __attribute__((ext_vector_type(4)));

#define MFMA_16x16x32 __builtin_amdgcn_mfma_f32_16x16x32_bf16

__device__ __forceinline__ ushort f2bf(float f) {            // RNE, finite inputs
    uint u = __float_as_uint(f);
    u += 0x7fffu + ((u >> 16) & 1u);
    return (ushort)(u >> 16);
}
__device__ __forceinline__ float bf2f(ushort h) {
    return __uint_as_float(((uint)h) << 16);
}

// ---------------------------------------------------------------------------
// split_rows: fp32 [n] -> bf16 hi/lo, same layout. Vectorized float4.
// ---------------------------------------------------------------------------
__global__ __launch_bounds__(256)
void split_rows(const float4* __restrict__ in, ushort4* __restrict__ hi,
                ushort4* __restrict__ lo, int n4)
{
    int i = blockIdx.x * 256 + threadIdx.x;
    int stride = gridDim.x * 256;
    for (; i < n4; i += stride) {
        float4 v = in[i];
        ushort4 h, l;
        h.x = f2bf(v.x); l.x = f2bf(v.x - bf2f(h.x));
        h.y = f2bf(v.y); l.y = f2bf(v.y - bf2f(h.y));
        h.z = f2bf(v.z); l.z = f2bf(v.z - bf2f(h.z));
        h.w = f2bf(v.w); l.w = f2bf(v.w - bf2f(h.w));
        hi[i] = h; lo[i] = l;
    }
}

// ---------------------------------------------------------------------------
// splitT: W fp32 [Kd][Nd] -> Wt bf16 hi/lo [Nd][Kd]. 64x64 LDS tile transpose.
// ---------------------------------------------------------------------------
__global__ __launch_bounds__(256)
void splitT(const float* __restrict__ W, ushort* __restrict__ th,
            ushort* __restrict__ tl, int Kd, int Nd)
{
    __shared__ float lds[64][65];
    const int n0 = blockIdx.x * 64, k0 = blockIdx.y * 64;
    const int c = threadIdx.x & 63, rb = threadIdx.x >> 6;
    #pragma unroll
    for (int i = 0; i < 16; i++) {
        int r = i * 4 + rb;
        lds[r][c] = W[(size_t)(k0 + r) * Nd + n0 + c];
    }
    __syncthreads();
    #pragma unroll
    for (int i = 0; i < 16; i++) {
        int r = i * 4 + rb;                    // n-local
        float v = lds[c][r];                   // [k-local][n-local]
        ushort hv = f2bf(v);
        size_t off = (size_t)(n0 + r) * Kd + k0 + c;
        th[off] = hv;
        tl[off] = f2bf(v - bf2f(hv));
    }
}

// ---------------------------------------------------------------------------
// Split-bf16 MFMA GEMM: C[M,N] = (Ah+Al)[M,K] @ (Bh+Bl)[N,K]^T, K=2048.
// Block 256 = 4 waves (2x2 of 64x64). Tile 128x128, BK=64.
// LDS 64KB: Ah | Al | Bh | Bl tiles, each [128 rows][64 bf16], XOR-swizzled
// (k-chunk g holds global chunk g^(row&7); same scheme as attn staging).
// MODE 0: fp32 out [M][N]
// MODE 1: bf16 hi/lo head layout [B,Hx,T,D] (Q, K)
// MODE 2: bf16 hi-only scatter to Vt [B,HK,D,T]
// ---------------------------------------------------------------------------
template<int MODE>
__global__ __launch_bounds__(256, 2)
void gemm_mfma(const ushort* __restrict__ Ah, const ushort* __restrict__ Al,
               const ushort* __restrict__ BTh, const ushort* __restrict__ BTl,
               float* __restrict__ outf, ushort* __restrict__ o_hi,
               ushort* __restrict__ o_lo, int N, int Hx)
{
    __shared__ __align__(16) char smem[65536];

    const int tid = threadIdx.x;
    const int w = tid >> 6, lane = tid & 63;
    const int g16 = lane >> 4, l16 = lane & 15;
    const int bm = blockIdx.y * 128, bn = blockIdx.x * 128;
    const int wm = (w >> 1) * 64, wn = (w & 1) * 64;

    // staging: wave w owns one array (0:Ah 1:Al 2:Bh 3:Bl)
    const ushort* sbase = (w == 0) ? Ah : (w == 1) ? Al : (w == 2) ? BTh : BTl;
    const int srow0 = (w < 2) ? bm : bn;
    const int r0 = lane >> 3, gg = lane & 7;

    f32x4 acc[4][4];
    #pragma unroll
    for (int mi = 0; mi < 4; mi++)
        #pragma unroll
        for (int ni = 0; ni < 4; ni++) acc[mi][ni] = (f32x4)0.f;

    for (int kt = 0; kt < Cc; kt += 64) {
        __syncthreads();
        #pragma unroll
        for (int i = 0; i < 16; i++) {
            int row = 8 * i + r0;
            const ushort* s = sbase + (size_t)(srow0 + row) * Cc + kt
                                    + ((gg ^ (row & 7)) * 8);
            u16x8 v = *(const u16x8*)s;
            *(u16x8*)&smem[w * 16384 + i * 1024 + lane * 16] = v;
        }
        __syncthreads();

        #pragma unroll
        for (int kf = 0; kf < 2; kf++) {
            bf16x8 a_h[4], a_l[4], b_h[4], b_l[4];
            #pragma unroll
            for (int mi = 0; mi < 4; mi++) {
                int row = wm + mi * 16 + l16;
                int byte = row * 128 + (((g16 + 4 * kf) ^ (row & 7)) * 16);
                a_h[mi] = *(const bf16x8*)&smem[byte];
                a_l[mi] = *(const bf16x8*)&smem[16384 + byte];
            }
            #pragma unroll
            for (int ni = 0; ni < 4; ni++) {
                int row = wn + ni * 16 + l16;
                int byte = row * 128 + (((g16 + 4 * kf) ^ (row & 7)) * 16);
                b_h[ni] = *(const bf16x8*)&smem[32768 + byte];
                b_l[ni] = *(const bf16x8*)&smem[49152 + byte];
            }
            #pragma unroll
            for (int mi = 0; mi < 4; mi++)
                #pragma unroll
                for (int ni = 0; ni < 4; ni++) {
                    acc[mi][ni] = MFMA_16x16x32(a_h[mi], b_h[ni], acc[mi][ni], 0, 0, 0);
                    acc[mi][ni] = MFMA_16x16x32(a_h[mi], b_l[ni], acc[mi][ni], 0, 0, 0);
                    acc[mi][ni] = MFMA_16x16x32(a_l[mi], b_h[ni], acc[mi][ni], 0, 0, 0);
                }
        }
    }

    // Epilogue. C mapping (verified): col = l16, row = g16*4 + r.
    #pragma unroll
    for (int mi = 0; mi < 4; mi++)
        #pragma unroll
        for (int r = 0; r < 4; r++) {
            int m = bm + wm + mi * 16 + g16 * 4 + r;
            if (MODE == 0) {
                float* op = outf + (size_t)m * N + bn + wn + l16;
                #pragma unroll
                for (int ni = 0; ni < 4; ni++) op[ni * 16] = acc[mi][ni][r];
            } else {
                int b = m >> 11, t = m & 2047;
                #pragma unroll
                for (int ni = 0; ni < 4; ni++) {
                    int n = bn + wn + ni * 16 + l16;
                    float v = acc[mi][ni][r];
                    ushort hv = f2bf(v);
                    if (MODE == 1) {
                        int h = n >> 7, d = n & 127;
                        size_t off = (((size_t)b * Hx + h) * Tt + t) * Dd + d;
                        o_hi[off] = hv;
                        o_lo[off] = f2bf(v - bf2f(hv));
                    } else {          // MODE 2: Vt [B,HK,D,T], hi only
                        int hk = n >> 7, d = n & 127;
                        size_t off = (((size_t)b * HKk + hk) * Dd + d) * Tt + t;
                        o_hi[off] = hv;
                    }
                }
            }
        }
}

// ---------------------------------------------------------------------------
// RoPE in place on bf16 hi/lo Q [B,H,T,D] and K [B,HK,T,D].
// ---------------------------------------------------------------------------
__global__ __launch_bounds__(256)
void rope_kernel(ushort* __restrict__ Qhi, ushort* __restrict__ Qlo,
                 ushort* __restrict__ Khi, ushort* __restrict__ Klo,
                 const int* __restrict__ positions)
{
    int idx = blockIdx.x * 256 + threadIdx.x;
    int i = idx & 63;
    int rest = idx >> 6;
    int t = rest % Tt;
    int bh = rest / Tt;
    int b = bh / (Hh + HKk);
    int h = bh % (Hh + HKk);

    ushort *hi, *lo;
    if (h < Hh) {
        size_t off = (((size_t)b * Hh + h) * Tt + t) * Dd;
        hi = Qhi + off; lo = Qlo + off;
    } else {
        size_t off = (((size_t)b * HKk + (h - Hh)) * Tt + t) * Dd;
        hi = Khi + off; lo = Klo + off;
    }

    float pos = (float)positions[t];
    float inv_theta = expf(-(2.0f * (float)i / 128.0f) * 9.210340371976184f);
    float f = pos * inv_theta;
    float s = sinf(f), co = cosf(f);

    float x1 = bf2f(hi[i])      + bf2f(lo[i]);
    float x2 = bf2f(hi[i + 64]) + bf2f(lo[i + 64]);
    float y1 = fmaf(x1, co, -x2 * s);
    float y2 = fmaf(x2, co,  x1 * s);

    ushort h1 = f2bf(y1); hi[i]      = h1; lo[i]      = f2bf(y1 - bf2f(h1));
    ushort h2 = f2bf(y2); hi[i + 64] = h2; lo[i + 64] = f2bf(y2 - bf2f(h2));
}

// ---------------------------------------------------------------------------
// Split-bf16 MFMA flash attention (validated round 4); epilogue emits
// bf16 hi/lo [B,T,H,D] so the Wo GEMM consumes it directly.
// ---------------------------------------------------------------------------
__global__ __launch_bounds__(256, 2)
void attn_mfma(const ushort* __restrict__ Qhi, const ushort* __restrict__ Qlo,
               const ushort* __restrict__ Khi, const ushort* __restrict__ Klo,
               const ushort* __restrict__ Vthi,
               ushort* __restrict__ Oh, ushort* __restrict__ Ol)
{
    __shared__ __align__(16) char smem[65536];

    const int tid  = threadIdx.x;
    const int w    = tid >> 6, lane = tid & 63;
    const int g16  = lane >> 4, l16 = lane & 15;

    int xb = blockIdx.x;
    int base = (xb & 1) ? 15 - (xb >> 1) : (xb >> 1);
    const int qt = blockIdx.z ? 15 - base : base;
    const int h = blockIdx.y, b = blockIdx.z, hk = h >> 1;

    bf16x8 qh[2][4], ql[2][4];
    {
        size_t qoff = (((size_t)b * Hh + h) * Tt + (size_t)qt * 128 + w * 32) * Dd;
        #pragma unroll
        for (int m = 0; m < 2; m++)
            #pragma unroll
            for (int kf = 0; kf < 4; kf++) {
                size_t o = qoff + (size_t)(m * 16 + l16) * Dd + g16 * 8 + kf * 32;
                qh[m][kf] = *(const bf16x8*)(Qhi + o);
                ql[m][kf] = *(const bf16x8*)(Qlo + o);
            }
    }

    const ushort* ksrc = (w == 0 ? Khi : Klo) + ((size_t)b * HKk + hk) * Tt * Dd;
    const ushort* vsrc = Vthi + ((size_t)b * HKk + hk) * Dd * Tt;
    char* Pbase = &smem[49152 + w * 4096];   // 32 rows x 128 B, hi only

    f32x4 acc[2][8];
    #pragma unroll
    for (int m = 0; m < 2; m++)
        #pragma unroll
        for (int nt = 0; nt < 8; nt++) acc[m][nt] = (f32x4)0.f;

    float mrun[8], lrun[8];
    #pragma unroll
    for (int i = 0; i < 8; i++) { mrun[i] = -INFINITY; lrun[i] = 0.f; }

    const int nkt    = 2 * qt + 2;
    const int qfirst = qt * 128 + w * 32;
    const int qlast  = qfirst + 31;
    const int prow0  = qfirst + 4 * g16;
    const float scl = 0.08838834764831845f;   // 1/sqrt(128)

    for (int kt = 0; kt < nkt; kt++) {
        __syncthreads();
        if (w < 2) {
            int rr = lane >> 4, g = lane & 15;
            #pragma unroll
            for (int i = 0; i < 16; i++) {
                int row = 4 * i + rr;
                const ushort* s = ksrc + (size_t)(kt * 64 + row) * Dd
                                       + ((g ^ (row & 7)) * 8);
                u16x8 v = *(const u16x8*)s;
                *(u16x8*)&smem[w * 16384 + i * 1024 + lane * 16] = v;
            }
        } else {
            int rr = lane >> 3, g = lane & 7;
            #pragma unroll
            for (int ii = 0; ii < 8; ii++) {
                int i = ii + (w - 2) * 8;
                int row = 8 * i + rr;                       // d
                const ushort* s = vsrc + (size_t)row * Tt + kt * 64
                                       + ((g ^ (row & 7)) * 8);
                u16x8 v = *(const u16x8*)s;
                *(u16x8*)&smem[32768 + i * 1024 + lane * 16] = v;
            }
        }
        __syncthreads();

        if (kt * 64 > qlast) continue;    // wave-uniform skip (barriers balanced)

        f32x4 s[2][4];
        #pragma unroll
        for (int m = 0; m < 2; m++)
            #pragma unroll
            for (int nt = 0; nt < 4; nt++) s[m][nt] = (f32x4)0.f;

        #pragma unroll
        for (int kf = 0; kf < 4; kf++) {
            #pragma unroll
            for (int nt = 0; nt < 4; nt++) {
                int row = l16 + nt * 16;                    // key
                int byte = row * 256 + (((g16 + 4 * kf) ^ (row & 7)) * 16);
                bf16x8 kh = *(const bf16x8*)&smem[byte];
                bf16x8 kl = *(const bf16x8*)&smem[16384 + byte];
                #pragma unroll
                for (int m = 0; m < 2; m++) {
                    s[m][nt] = MFMA_16x16x32(qh[m][kf], kh, s[m][nt], 0, 0, 0);
                    s[m][nt] = MFMA_16x16x32(qh[m][kf], kl, s[m][nt], 0, 0, 0);
                    s[m][nt] = MFMA_16x16x32(ql[m][kf], kh, s[m][nt], 0, 0, 0);
                }
            }
        }

        bool partial = (kt * 64 + 63 > qfirst);
        #pragma unroll
        for (int m = 0; m < 2; m++)
            #pragma unroll
            for (int nt = 0; nt < 4; nt++) {
                s[m][nt] *= scl;
                if (partial) {
                    int col = kt * 64 + nt * 16 + l16;
                    #pragma unroll
                    for (int r = 0; r < 4; r++) {
                        int row = prow0 + m * 16 + r;
                        if (col > row) s[m][nt][r] = -INFINITY;
                    }
                }
            }

        #pragma unroll
        for (int m = 0; m < 2; m++)
            #pragma unroll
            for (int r = 0; r < 4; r++) {
                float mx = fmaxf(fmaxf(s[m][0][r], s[m][1][r]),
                                 fmaxf(s[m][2][r], s[m][3][r]));
                #pragma unroll
                for (int o = 1; o < 16; o <<= 1)
                    mx = fmaxf(mx, __shfl_xor(mx, o, 16));
                int ri = m * 4 + r;
                float mn  = fmaxf(mrun[ri], mx);
                float fac = __expf(mrun[ri] - mn);
                float sum = 0.f;
                #pragma unroll
                for (int nt = 0; nt < 4; nt++) {
                    float pv = __expf(s[m][nt][r] - mn);
                    s[m][nt][r] = pv;
                    sum += pv;
                }
                #pragma unroll
                for (int o = 1; o < 16; o <<= 1)
                    sum += __shfl_xor(sum, o, 16);
                lrun[ri] = lrun[ri] * fac + sum;
                mrun[ri] = mn;
                #pragma unroll
                for (int nt = 0; nt < 8; nt++) acc[m][nt][r] *= fac;
            }

        #pragma unroll
        for (int m = 0; m < 2; m++)
            #pragma unroll
            for (int nt = 0; nt < 4; nt++)
                #pragma unroll
                for (int r = 0; r < 4; r++) {
                    int row = m * 16 + 4 * g16 + r;
                    int byte = (row * 128 + (nt * 16 + l16) * 2) ^ ((row & 7) << 4);
                    *(ushort*)(Pbase + byte) = f2bf(s[m][nt][r]);
                }

        #pragma unroll
        for (int kf = 0; kf < 2; kf++) {
            bf16x8 pa[2];
            #pragma unroll
            for (int m = 0; m < 2; m++) {
                int row = m * 16 + l16;
                int byte = (row * 128 + (g16 + 4 * kf) * 16) ^ ((row & 7) << 4);
                pa[m] = *(const bf16x8*)(Pbase + byte);
            }
            #pragma unroll
            for (int nt = 0; nt < 8; nt++) {
                int row = l16 + nt * 16;                    // d
                int byte = 32768 + row * 128 + (((g16 + 4 * kf) ^ (row & 7)) * 16);
                bf16x8 vh = *(const bf16x8*)&smem[byte];
                #pragma unroll
                for (int m = 0; m < 2; m++)
                    acc[m][nt] = MFMA_16x16x32(pa[m], vh, acc[m][nt], 0, 0, 0);
            }
        }
    }

    // epilogue: normalize, emit bf16 hi/lo attn buffer [B,T,H,D]
    #pragma unroll
    for (int m = 0; m < 2; m++)
        #pragma unroll
        for (int r = 0; r < 4; r++) {
            float inv = 1.0f / lrun[m * 4 + r];
            int t = qt * 128 + w * 32 + m * 16 + 4 * g16 + r;
            size_t ob = (((size_t)b * Tt + t) * Hh + h) * Dd + l16;
            #pragma unroll
            for (int nt = 0; nt < 8; nt++) {
                float v = acc[m][nt][r] * inv;
                ushort hv = f2bf(v);
                Oh[ob + nt * 16] = hv;
                Ol[ob + nt * 16] = f2bf(v - bf2f(hv));
            }
        }
}

// ---------------------------------------------------------------------------
// Launch. ws layout (bytes), peak exactly 100,663,296.
// RACE FIX vs round 6: every dispatch's read-set and write-set are disjoint.
//   [0,        16.78M)  xh            -> Awh (after attention; x dead)
//   [16.78M,   33.55M)  xl            -> Awl
//   [33.55M,   50.33M)  Qhi
//   [50.33M,   67.11M)  Qlo
//   [67.11M,   83.89M)  WtQh+WtQl -> Khi+Klo (WtQ dead) -> WtOh+WtOl (K dead)
//   [83.89M,   92.27M)  WtKh+WtKl -> Vt (full 8.39M slot; WtK dead)
//   [92.27M,  100.66M)  WtVh+WtVl   (disjoint from Vt -- was the race)
// ---------------------------------------------------------------------------
extern "C" void kernel_launch(void* const* d_in, const int* in_sizes, int n_in,
                              void* d_out, int out_size, void* d_ws, size_t ws_size,
                              hipStream_t stream)
{
    const float* x  = (const float*)d_in[0];
    const int*   pos = (const int*)d_in[2];
    const float* Wq = (const float*)d_in[3];
    const float* Wk = (const float*)d_in[4];
    const float* Wv = (const float*)d_in[5];
    const float* Wo = (const float*)d_in[6];
    float* out = (float*)d_out;

    char* p = (char*)d_ws;
    ushort* xh   = (ushort*)(p);
    ushort* xl   = (ushort*)(p + 16777216);
    ushort* Awh  = xh;                            // alias after x is dead
    ushort* Awl  = xl;
    ushort* Qhi  = (ushort*)(p + 33554432);
    ushort* Qlo  = (ushort*)(p + 50331648);
    ushort* WtQh = (ushort*)(p + 67108864);       // 8.39M
    ushort* WtQl = (ushort*)(p + 75497472);       // 8.39M
    ushort* Khi  = (ushort*)(p + 67108864);       // after WtQ dead
    ushort* Klo  = (ushort*)(p + 75497472);
    ushort* WtOh = (ushort*)(p + 67108864);       // after attention (K dead)
    ushort* WtOl = (ushort*)(p + 75497472);
    ushort* WtKh = (ushort*)(p + 83886080);       // 4.19M
    ushort* WtKl = (ushort*)(p + 88080384);       // 4.19M
    ushort* Vt   = (ushort*)(p + 83886080);       // 8.39M, after WtK dead
    ushort* WtVh = (ushort*)(p + 92274688);       // 4.19M
    ushort* WtVl = (ushort*)(p + 96468992);       // 4.19M, ends at 100,663,296

    dim3 blk(256);

    // 1. split x -> bf16 hi/lo
    split_rows<<<2048, blk, 0, stream>>>((const float4*)x, (ushort4*)xh,
                                         (ushort4*)xl, Bb * Tt * Cc / 4);
    // 2-3. Q projection (reads x, WtQ; writes Q -- disjoint)
    splitT<<<dim3(32, 32), blk, 0, stream>>>(Wq, WtQh, WtQl, Cc, Hh * Dd);
    gemm_mfma<1><<<dim3(16, 32), blk, 0, stream>>>(xh, xl, WtQh, WtQl,
                                                   nullptr, Qhi, Qlo, Hh * Dd, Hh);
    // 4-5. K projection (reads x, WtK; writes K over dead WtQ -- disjoint)
    splitT<<<dim3(16, 32), blk, 0, stream>>>(Wk, WtKh, WtKl, Cc, HKk * Dd);
    gemm_mfma<1><<<dim3(8, 32), blk, 0, stream>>>(xh, xl, WtKh, WtKl,
                                                  nullptr, Khi, Klo, HKk * Dd, HKk);
    // 6-7. V projection (reads x, WtV; writes Vt over dead WtK -- disjoint)
    splitT<<<dim3(16, 32), blk, 0, stream>>>(Wv, WtVh, WtVl, Cc, HKk * Dd);
    gemm_mfma<2><<<dim3(8, 32), blk, 0, stream>>>(xh, xl, WtVh, WtVl,
                                                  nullptr, Vt, nullptr, HKk * Dd, HKk);
    // 8. RoPE on Q, K (in place)
    {
        int total = Bb * (Hh + HKk) * Tt * 64;
        rope_kernel<<<total / 256, blk, 0, stream>>>(Qhi, Qlo, Khi, Klo, pos);
    }
    // 9. attention -> Aw bf16 hi/lo (into R0; x is dead)
    attn_mfma<<<dim3(16, Hh, Bb), blk, 0, stream>>>(Qhi, Qlo, Khi, Klo, Vt, Awh, Awl);
    // 10-11. output projection (WtO over dead K; reads Aw; writes d_out)
    splitT<<<dim3(32, 32), blk, 0, stream>>>(Wo, WtOh, WtOl, Hh * Dd, Cc);
    gemm_mfma<0><<<dim3(16, 32), blk, 0, stream>>>(Awh, Awl, WtOh, WtOl,
                                                   out, nullptr, nullptr, Cc, 0);
}